// Round 3
// baseline (125.413 us; speedup 1.0000x reference)
//
#include <hip/hip_runtime.h>

typedef __attribute__((ext_vector_type(4))) int   i32x4;
typedef __attribute__((ext_vector_type(4))) float f32x4;

#define TF    32768   // T*F
#define TF4   8192    // TF/4
#define NS    2048    // N samples

// mask accessor: isI32 ? int32[] : byte-bool[]
__device__ __forceinline__ i32x4 mload4(const void* mask, int isI32, int idx4) {
  if (isI32) return ((const i32x4*)mask)[idx4];
  unsigned int w = ((const unsigned int*)mask)[idx4];
  i32x4 r;
  r[0] = (int)(w & 0xFFu);
  r[1] = (int)((w >> 8) & 0xFFu);
  r[2] = (int)((w >> 16) & 0xFFu);
  r[3] = (int)((w >> 24) & 0xFFu);
  return r;
}

__device__ __forceinline__ double ac_fn(int t) {
  const double s = 0.008;
  double c = cos(((double)t / 1000.0 + s) / (1.0 + s) * 1.5707963267948966);
  return c * c;
}
__device__ __forceinline__ double alpha_fn(int t) {
  double beta = 1.0 - ac_fn(t + 1) / ac_fn(t);
  beta = beta < 0.0 ? 0.0 : (beta > 0.999 ? 0.999 : beta);
  return 1.0 - beta;
}

// ---------- K1: mask-dtype probe + schedule scalars + pred table ----------
__launch_bounds__(256)
__global__ void k1_sched(const int* __restrict__ ip,
                         const float* __restrict__ timep,
                         const float* __restrict__ dega,
                         const float* __restrict__ degb,
                         const unsigned int* __restrict__ maskw,
                         float* __restrict__ wsc, float* __restrict__ pred) {
  const int tid = threadIdx.x;

  // --- probe mask storage: first 32768 bytes as u32 words ---
  __shared__ int badsh;
  if (tid == 0) badsh = 0;
  __syncthreads();
  int bad = 0;
  for (int k = tid; k < TF4; k += 256)
    if (maskw[k] > 1u) bad = 1;          // int32 0/1 mask never triggers
  if (bad) atomicOr(&badsh, 1);

  // --- cumulative product of alphas over t=0..i-1 (f64, like ref) ---
  const int i = ip[0];
  __shared__ double prod[256];
  double p = 1.0;
  for (int t = tid; t < i; t += 256) p *= alpha_fn(t);
  prod[tid] = p;
  __syncthreads();
  for (int s = 128; s > 0; s >>= 1) {
    if (tid < s) prod[tid] *= prod[tid + s];
    __syncthreads();
  }
  if (tid == 0) {
    double acp_im1 = prod[0];
    double ai = alpha_fn(i);
    double acp_i = acp_im1 * ai;
    wsc[0] = (float)sqrt(1.0 - acp_i);  // sigma_i
    wsc[1] = (float)acp_i;              // abar_i
    wsc[2] = (float)ai;                 // alpha_i
    wsc[3] = (float)acp_im1;            // abar_{i-1}
    ((int*)wsc)[8] = badsh ? 0 : 1;     // 1 = mask stored as int32
  }

  // --- pred[t,f] = a[f] + b[f]*time[t] ---
  for (int idx = tid; idx < TF; idx += 256) {
    int t = idx >> 6, f = idx & 63;
    pred[idx] = fmaf(degb[f], timep[t], dega[f]);
  }
}

// ---------- K2: per-sample scores (4 samples per block) ----------
__launch_bounds__(256)
__global__ void k2_scores(const float* __restrict__ eps,
                          const float* __restrict__ xbar,
                          const float* __restrict__ obs,
                          const void* __restrict__ mask,
                          const float* __restrict__ pred,
                          const float* __restrict__ wsc,
                          float* __restrict__ scores) {
  const int tid = threadIdx.x;
  const int n0 = blockIdx.x * 4;
  const float sig = wsc[0];
  const int isI32 = ((const int*)wsc)[8];
  const f32x4* e4 = (const f32x4*)eps;
  const f32x4* x4 = (const f32x4*)xbar;
  const f32x4* o4 = (const f32x4*)obs;
  const f32x4* p4 = (const f32x4*)pred;

  double acc[4] = {0.0, 0.0, 0.0, 0.0};
  double oacc = 0.0;
  for (int k = tid; k < TF4; k += 256) {
    f32x4 x = x4[k], o = o4[k], pr = p4[k];
    i32x4 m = mload4(mask, isI32, k);
    float sc[4], xq[4], pq[4];
    float od2 = 0.f;
    #pragma unroll
    for (int c = 0; c < 4; ++c) {
      const bool mm = m[c] != 0;
      sc[c] = mm ? 0.f : sig;       // kill eps at observed positions
      xq[c] = mm ? 0.f : x[c];      // there: v=clip(0)=0, d=0
      pq[c] = mm ? 0.f : pr[c];
      float d = o[c] - pr[c];
      od2 += mm ? d * d : 0.f;      // constant observed contribution, once
    }
    oacc += (double)od2;
    #pragma unroll
    for (int r = 0; r < 4; ++r) {
      f32x4 e = e4[(size_t)(n0 + r) * TF4 + k];
      float s = 0.f;
      #pragma unroll
      for (int c = 0; c < 4; ++c) {
        float v = fmaf(e[c], sc[c], xq[c]);
        v = fminf(fmaxf(v, -1.f), 1.f);
        float d = v - pq[c];
        s = fmaf(d, d, s);
      }
      acc[r] += (double)s;
    }
  }
  __shared__ double red[4 * 256];
  __shared__ double rob[256];
  #pragma unroll
  for (int r = 0; r < 4; ++r) red[r * 256 + tid] = acc[r];
  rob[tid] = oacc;
  __syncthreads();
  for (int s = 128; s > 0; s >>= 1) {
    if (tid < s) {
      #pragma unroll
      for (int r = 0; r < 4; ++r) red[r * 256 + tid] += red[r * 256 + tid + s];
      rob[tid] += rob[tid + s];
    }
    __syncthreads();
  }
  if (tid < 4)
    scores[n0 + tid] = -(float)((red[tid * 256] + rob[0]) * (1.0 / 32768.0));
}

// ---------- K3: normalized softmax weights ----------
__launch_bounds__(256)
__global__ void k3_softmax(const float* __restrict__ scores,
                           float* __restrict__ weights) {
  const int tid = threadIdx.x;
  __shared__ double red[256];
  float s[8];
  #pragma unroll
  for (int j = 0; j < 8; ++j) s[j] = scores[tid + 256 * j];
  double t = 0.0;
  #pragma unroll
  for (int j = 0; j < 8; ++j) t += (double)s[j];
  red[tid] = t; __syncthreads();
  for (int st = 128; st > 0; st >>= 1) { if (tid < st) red[tid] += red[tid + st]; __syncthreads(); }
  const float mean = (float)(red[0] * (1.0 / 2048.0));
  __syncthreads();
  double v = 0.0;
  #pragma unroll
  for (int j = 0; j < 8; ++j) { float d = s[j] - mean; v += (double)d * (double)d; }
  red[tid] = v; __syncthreads();
  for (int st = 128; st > 0; st >>= 1) { if (tid < st) red[tid] += red[tid + st]; __syncthreads(); }
  float stdv = (float)sqrt(red[0] / 2047.0);   // ddof=1
  stdv = fmaxf(stdv, 1e-4f);
  const float inv = 10.0f / stdv;              // /std /0.1
  float lp[8];
  double mx = -1e300;
  #pragma unroll
  for (int j = 0; j < 8; ++j) { lp[j] = (s[j] - mean) * inv; mx = fmax(mx, (double)lp[j]); }
  __syncthreads();
  red[tid] = mx; __syncthreads();
  for (int st = 128; st > 0; st >>= 1) { if (tid < st) red[tid] = fmax(red[tid], red[tid + st]); __syncthreads(); }
  const float M = (float)red[0];
  __syncthreads();
  float ev[8]; double es = 0.0;
  #pragma unroll
  for (int j = 0; j < 8; ++j) { ev[j] = expf(lp[j] - M); es += (double)ev[j]; }
  red[tid] = es; __syncthreads();
  for (int st = 128; st > 0; st >>= 1) { if (tid < st) red[tid] += red[tid + st]; __syncthreads(); }
  const float invS = (float)(1.0 / red[0]);
  #pragma unroll
  for (int j = 0; j < 8; ++j) weights[tid + 256 * j] = ev[j] * invS;
}

// ---------- K4: weighted = sum_n w_n * clip(eps*sig + Xbar) (partials) ----------
__launch_bounds__(256)
__global__ void k4_weighted(const float* __restrict__ eps,
                            const float* __restrict__ xbar,
                            const float* __restrict__ weights,
                            const float* __restrict__ wsc,
                            float* __restrict__ partial) {
  const int tid = threadIdx.x;
  const int pos4 = blockIdx.x * 256 + tid;   // 0..8191
  const int g = blockIdx.y;                  // 0..15 (groups of 128 samples)
  const float sig = wsc[0];
  const f32x4* e4 = (const f32x4*)eps;
  f32x4 xf = ((const f32x4*)xbar)[pos4];
  f32x4 acc = {0.f, 0.f, 0.f, 0.f};
  const int nb = g * 128;
  #pragma unroll 4
  for (int j = 0; j < 128; ++j) {
    const float w = weights[nb + j];
    f32x4 e = e4[(size_t)(nb + j) * TF4 + pos4];
    #pragma unroll
    for (int c = 0; c < 4; ++c) {
      float v = fmaf(e[c], sig, xf[c]);
      v = fminf(fmaxf(v, -1.f), 1.f);
      acc[c] = fmaf(w, v, acc[c]);
    }
  }
  ((f32x4*)partial)[(size_t)g * TF4 + pos4] = acc;
}

// ---------- K5: reduce partials + final combine -> f32 out ----------
__launch_bounds__(256)
__global__ void k5_final(const float* __restrict__ partial,
                         const float* __restrict__ xbar,
                         const float* __restrict__ obs,
                         const void* __restrict__ mask,
                         const float* __restrict__ wsc,
                         float* __restrict__ out) {
  const int pos4 = blockIdx.x * 256 + threadIdx.x;  // grid 32
  const f32x4* p4 = (const f32x4*)partial;
  f32x4 w = {0.f, 0.f, 0.f, 0.f};
  #pragma unroll
  for (int g = 0; g < 16; ++g) {
    f32x4 a = p4[(size_t)g * TF4 + pos4];
    #pragma unroll
    for (int c = 0; c < 4; ++c) w[c] += a[c];
  }
  const float abar = wsc[1];
  const float sa = sqrtf(abar);
  const float ra = 1.f / sqrtf(wsc[2]);
  const float rb = 1.f / sqrtf(wsc[3]);
  const int isI32 = ((const int*)wsc)[8];
  f32x4 xf = ((const f32x4*)xbar)[pos4];
  f32x4 ov = ((const f32x4*)obs)[pos4];
  i32x4 m = mload4(mask, isI32, pos4);
  f32x4 res;
  #pragma unroll
  for (int c = 0; c < 4; ++c) {
    const float Yi = sa * xf[c];
    const float scv = (-Yi + sa * w[c]) / (1.f - abar);
    const float xim1 = (Yi + (1.f - abar) * scv) * ra;
    res[c] = m[c] ? ov[c] : (xim1 * rb);
  }
  ((f32x4*)out)[pos4] = res;
}

extern "C" void kernel_launch(void* const* d_in, const int* in_sizes, int n_in,
                              void* d_out, int out_size, void* d_ws, size_t ws_size,
                              hipStream_t stream) {
  const float* Xbar  = (const float*)d_in[0];
  const float* obs   = (const float*)d_in[1];
  const float* timep = (const float*)d_in[2];
  const void*  mask  = d_in[3];
  const float* eps   = (const float*)d_in[4];
  const float* dega  = (const float*)d_in[5];
  const float* degb  = (const float*)d_in[6];
  const int*   ip    = (const int*)d_in[7];

  float* ws      = (float*)d_ws;
  float* wsc     = ws;                    // 16 floats (incl. mask-dtype flag)
  float* pred    = ws + 16;               // 32768
  float* scores  = pred + TF;             // 2048
  float* weights = scores + NS;           // 2048
  float* partial = weights + NS;          // 16 * 32768 floats (2 MiB)

  hipLaunchKernelGGL(k1_sched,   dim3(1),      dim3(256), 0, stream,
                     ip, timep, dega, degb, (const unsigned int*)mask, wsc, pred);
  hipLaunchKernelGGL(k2_scores,  dim3(NS/4),   dim3(256), 0, stream,
                     eps, Xbar, obs, mask, pred, wsc, scores);
  hipLaunchKernelGGL(k3_softmax, dim3(1),      dim3(256), 0, stream, scores, weights);
  hipLaunchKernelGGL(k4_weighted,dim3(32, 16), dim3(256), 0, stream,
                     eps, Xbar, weights, wsc, partial);
  hipLaunchKernelGGL(k5_final,   dim3(32),     dim3(256), 0, stream,
                     partial, Xbar, obs, mask, wsc, (float*)d_out);
}

// Round 4
// 79.195 us; speedup vs baseline: 1.5836x; 1.5836x over previous
//
#include <hip/hip_runtime.h>

typedef __attribute__((ext_vector_type(4))) int   i32x4;
typedef __attribute__((ext_vector_type(4))) float f32x4;

#define TF    32768   // T*F
#define TF4   8192    // TF/4
#define NS    2048    // N samples
#define WCUT  1e-9f   // weight cutoff: skipped mass <= 2048*1e-9 ~ 2e-6

// mask accessor: isI32 ? int32[] : byte-bool[]
__device__ __forceinline__ i32x4 mload4(const void* mask, int isI32, int idx4) {
  if (isI32) return ((const i32x4*)mask)[idx4];
  unsigned int w = ((const unsigned int*)mask)[idx4];
  i32x4 r;
  r[0] = (int)(w & 0xFFu);
  r[1] = (int)((w >> 8) & 0xFFu);
  r[2] = (int)((w >> 16) & 0xFFu);
  r[3] = (int)((w >> 24) & 0xFFu);
  return r;
}

__device__ __forceinline__ double ac_fn(int t) {
  const double s = 0.008;
  double c = cos(((double)t / 1000.0 + s) / (1.0 + s) * 1.5707963267948966);
  return c * c;
}
__device__ __forceinline__ double alpha_fn(int t) {
  double beta = 1.0 - ac_fn(t + 1) / ac_fn(t);
  beta = beta < 0.0 ? 0.0 : (beta > 0.999 ? 0.999 : beta);
  return 1.0 - beta;
}

// ---------- K1a: mask-dtype probe + schedule scalars (1 block) ----------
__launch_bounds__(256)
__global__ void k1a_sched(const int* __restrict__ ip,
                          const unsigned int* __restrict__ maskw,
                          float* __restrict__ wsc) {
  const int tid = threadIdx.x;
  __shared__ int badsh;
  if (tid == 0) badsh = 0;
  __syncthreads();
  int bad = 0;
  for (int k = tid; k < TF4; k += 256)
    if (maskw[k] > 1u) bad = 1;          // int32 0/1 mask never triggers
  if (bad) atomicOr(&badsh, 1);

  const int i = ip[0];
  __shared__ double prod[256];
  double p = 1.0;
  for (int t = tid; t < i; t += 256) p *= alpha_fn(t);
  prod[tid] = p;
  __syncthreads();
  for (int s = 128; s > 0; s >>= 1) {
    if (tid < s) prod[tid] *= prod[tid + s];
    __syncthreads();
  }
  if (tid == 0) {
    double acp_im1 = prod[0];
    double ai = alpha_fn(i);
    double acp_i = acp_im1 * ai;
    wsc[0] = (float)sqrt(1.0 - acp_i);  // sigma_i
    wsc[1] = (float)acp_i;              // abar_i
    wsc[2] = (float)ai;                 // alpha_i
    wsc[3] = (float)acp_im1;            // abar_{i-1}
    ((int*)wsc)[8] = badsh ? 0 : 1;     // 1 = mask stored as int32
  }
}

// ---------- K1b: fused per-position streams + observed-const (grid 32) ----------
__launch_bounds__(256)
__global__ void k1b_tables(const float* __restrict__ xbar,
                           const float* __restrict__ obs,
                           const void* __restrict__ mask,
                           const float* __restrict__ timep,
                           const float* __restrict__ dega,
                           const float* __restrict__ degb,
                           const float* __restrict__ wsc,
                           float* __restrict__ sc, float* __restrict__ xq,
                           float* __restrict__ pq, double* __restrict__ osum_part) {
  const int tid = threadIdx.x;
  const int pos4 = blockIdx.x * 256 + tid;   // 0..8191
  const float sig = wsc[0];
  const int isI32 = ((const int*)wsc)[8];

  const int t  = pos4 >> 4;          // (4*pos4)>>6
  const int f0 = (pos4 << 2) & 63;
  const float tv = timep[t];
  f32x4 da = *(const f32x4*)(dega + f0);
  f32x4 db = *(const f32x4*)(degb + f0);
  f32x4 x  = ((const f32x4*)xbar)[pos4];
  f32x4 o  = ((const f32x4*)obs)[pos4];
  i32x4 m  = mload4(mask, isI32, pos4);

  f32x4 scv, xqv, pqv;
  float od2 = 0.f;
  #pragma unroll
  for (int c = 0; c < 4; ++c) {
    const float pr = fmaf(db[c], tv, da[c]);
    const bool mm = m[c] != 0;
    scv[c] = mm ? 0.f : sig;
    xqv[c] = mm ? 0.f : x[c];
    pqv[c] = mm ? 0.f : pr;
    float d = o[c] - pr;
    od2 += mm ? d * d : 0.f;
  }
  ((f32x4*)sc)[pos4] = scv;
  ((f32x4*)xq)[pos4] = xqv;
  ((f32x4*)pq)[pos4] = pqv;

  __shared__ double red[256];
  red[tid] = (double)od2;
  __syncthreads();
  for (int s = 128; s > 0; s >>= 1) {
    if (tid < s) red[tid] += red[tid + s];
    __syncthreads();
  }
  if (tid == 0) osum_part[blockIdx.x] = red[0];
}

// ---------- K2: per-sample score partials (4 samples x 2 k-halves) ----------
__launch_bounds__(256)
__global__ void k2_scores(const float* __restrict__ eps,
                          const float* __restrict__ sc,
                          const float* __restrict__ xq,
                          const float* __restrict__ pq,
                          double* __restrict__ pscore) {
  const int tid = threadIdx.x;
  const int n0 = blockIdx.x * 4;
  const int kh = blockIdx.y;
  const int kbeg = kh * (TF4 / 2);
  const f32x4* e4 = (const f32x4*)eps;
  const f32x4* sc4 = (const f32x4*)sc;
  const f32x4* xq4 = (const f32x4*)xq;
  const f32x4* pq4 = (const f32x4*)pq;

  double acc[4] = {0.0, 0.0, 0.0, 0.0};
  for (int k = kbeg + tid; k < kbeg + TF4 / 2; k += 256) {
    f32x4 scv = sc4[k], xqv = xq4[k], pqv = pq4[k];
    #pragma unroll
    for (int r = 0; r < 4; ++r) {
      f32x4 e = e4[(size_t)(n0 + r) * TF4 + k];
      float s = 0.f;
      #pragma unroll
      for (int c = 0; c < 4; ++c) {
        float v = fmaf(e[c], scv[c], xqv[c]);
        v = fminf(fmaxf(v, -1.f), 1.f);
        float d = v - pqv[c];
        s = fmaf(d, d, s);
      }
      acc[r] += (double)s;
    }
  }
  __shared__ double red[4 * 256];
  #pragma unroll
  for (int r = 0; r < 4; ++r) red[r * 256 + tid] = acc[r];
  __syncthreads();
  for (int s = 128; s > 0; s >>= 1) {
    if (tid < s) {
      #pragma unroll
      for (int r = 0; r < 4; ++r) red[r * 256 + tid] += red[r * 256 + tid + s];
    }
    __syncthreads();
  }
  if (tid < 4) pscore[kh * NS + n0 + tid] = red[tid * 256];
}

// ---------- K3: softmax + deterministic compaction ----------
__launch_bounds__(256)
__global__ void k3_softmax(const double* __restrict__ pscore,
                           const double* __restrict__ osum_part,
                           float* __restrict__ wsc,
                           int* __restrict__ cidx, float* __restrict__ cw) {
  const int tid = threadIdx.x;
  __shared__ double red[256];

  // observed-constant
  double osum = 0.0;
  if (tid < 32) osum = osum_part[tid];
  red[tid] = osum; __syncthreads();
  for (int st = 128; st > 0; st >>= 1) { if (tid < st) red[tid] += red[tid + st]; __syncthreads(); }
  osum = red[0];
  __syncthreads();

  float s[8];
  #pragma unroll
  for (int j = 0; j < 8; ++j) {
    int n = tid + 256 * j;
    s[j] = -(float)((pscore[n] + pscore[NS + n] + osum) * (1.0 / 32768.0));
  }
  double t = 0.0;
  #pragma unroll
  for (int j = 0; j < 8; ++j) t += (double)s[j];
  red[tid] = t; __syncthreads();
  for (int st = 128; st > 0; st >>= 1) { if (tid < st) red[tid] += red[tid + st]; __syncthreads(); }
  const float mean = (float)(red[0] * (1.0 / 2048.0));
  __syncthreads();
  double v = 0.0;
  #pragma unroll
  for (int j = 0; j < 8; ++j) { float d = s[j] - mean; v += (double)d * (double)d; }
  red[tid] = v; __syncthreads();
  for (int st = 128; st > 0; st >>= 1) { if (tid < st) red[tid] += red[tid + st]; __syncthreads(); }
  float stdv = (float)sqrt(red[0] / 2047.0);   // ddof=1
  stdv = fmaxf(stdv, 1e-4f);
  const float inv = 10.0f / stdv;              // /std /0.1
  float lp[8];
  double mx = -1e300;
  #pragma unroll
  for (int j = 0; j < 8; ++j) { lp[j] = (s[j] - mean) * inv; mx = fmax(mx, (double)lp[j]); }
  __syncthreads();
  red[tid] = mx; __syncthreads();
  for (int st = 128; st > 0; st >>= 1) { if (tid < st) red[tid] = fmax(red[tid], red[tid + st]); __syncthreads(); }
  const float M = (float)red[0];
  __syncthreads();
  float ev[8]; double es = 0.0;
  #pragma unroll
  for (int j = 0; j < 8; ++j) { ev[j] = expf(lp[j] - M); es += (double)ev[j]; }
  red[tid] = es; __syncthreads();
  for (int st = 128; st > 0; st >>= 1) { if (tid < st) red[tid] += red[tid + st]; __syncthreads(); }
  const float invS = (float)(1.0 / red[0]);

  // weights + deterministic compaction (prefix scan over per-thread counts)
  float w[8]; int keep[8]; int c = 0;
  #pragma unroll
  for (int j = 0; j < 8; ++j) {
    w[j] = ev[j] * invS;
    keep[j] = w[j] > WCUT;
    c += keep[j];
  }
  __shared__ int cnt[256];
  cnt[tid] = c; __syncthreads();
  for (int off = 1; off < 256; off <<= 1) {
    int vv = (tid >= off) ? cnt[tid - off] : 0;
    __syncthreads();
    cnt[tid] += vv;
    __syncthreads();
  }
  int base = cnt[tid] - c;              // exclusive prefix
  #pragma unroll
  for (int j = 0; j < 8; ++j) {
    if (keep[j]) {
      cidx[base] = tid + 256 * j;
      cw[base] = w[j];
      ++base;
    }
  }
  if (tid == 255) ((int*)wsc)[9] = cnt[255];   // Nk
}

// ---------- K4: weighted sum over kept samples only ----------
__launch_bounds__(256)
__global__ void k4_weighted(const float* __restrict__ eps,
                            const float* __restrict__ xq_unused,
                            const int* __restrict__ cidx,
                            const float* __restrict__ cw,
                            const float* __restrict__ wsc,
                            const float* __restrict__ xbar,
                            float* __restrict__ partial) {
  const int tid = threadIdx.x;
  const int pos4 = blockIdx.x * 256 + tid;   // 0..8191
  const int g = blockIdx.y;                  // 0..15
  const int Nk = ((const int*)wsc)[9];
  const float sig = wsc[0];
  const f32x4* e4 = (const f32x4*)eps;
  f32x4 xf = ((const f32x4*)xbar)[pos4];
  f32x4 acc = {0.f, 0.f, 0.f, 0.f};
  for (int j = g; j < Nk; j += 16) {
    const float w = cw[j];
    const int n = cidx[j];
    f32x4 e = e4[(size_t)n * TF4 + pos4];
    #pragma unroll
    for (int c = 0; c < 4; ++c) {
      float v = fmaf(e[c], sig, xf[c]);
      v = fminf(fmaxf(v, -1.f), 1.f);
      acc[c] = fmaf(w, v, acc[c]);
    }
  }
  ((f32x4*)partial)[(size_t)g * TF4 + pos4] = acc;
}

// ---------- K5: reduce partials + final combine -> f32 out ----------
__launch_bounds__(256)
__global__ void k5_final(const float* __restrict__ partial,
                         const float* __restrict__ xbar,
                         const float* __restrict__ obs,
                         const void* __restrict__ mask,
                         const float* __restrict__ wsc,
                         float* __restrict__ out) {
  const int pos4 = blockIdx.x * 256 + threadIdx.x;  // grid 32
  const f32x4* p4 = (const f32x4*)partial;
  f32x4 w = {0.f, 0.f, 0.f, 0.f};
  #pragma unroll
  for (int g = 0; g < 16; ++g) {
    f32x4 a = p4[(size_t)g * TF4 + pos4];
    #pragma unroll
    for (int c = 0; c < 4; ++c) w[c] += a[c];
  }
  const float abar = wsc[1];
  const float sa = sqrtf(abar);
  const float ra = 1.f / sqrtf(wsc[2]);
  const float rb = 1.f / sqrtf(wsc[3]);
  const int isI32 = ((const int*)wsc)[8];
  f32x4 xf = ((const f32x4*)xbar)[pos4];
  f32x4 ov = ((const f32x4*)obs)[pos4];
  i32x4 m = mload4(mask, isI32, pos4);
  f32x4 res;
  #pragma unroll
  for (int c = 0; c < 4; ++c) {
    const float Yi = sa * xf[c];
    const float scv = (-Yi + sa * w[c]) / (1.f - abar);
    const float xim1 = (Yi + (1.f - abar) * scv) * ra;
    res[c] = m[c] ? ov[c] : (xim1 * rb);
  }
  ((f32x4*)out)[pos4] = res;
}

extern "C" void kernel_launch(void* const* d_in, const int* in_sizes, int n_in,
                              void* d_out, int out_size, void* d_ws, size_t ws_size,
                              hipStream_t stream) {
  const float* Xbar  = (const float*)d_in[0];
  const float* obs   = (const float*)d_in[1];
  const float* timep = (const float*)d_in[2];
  const void*  mask  = d_in[3];
  const float* eps   = (const float*)d_in[4];
  const float* dega  = (const float*)d_in[5];
  const float* degb  = (const float*)d_in[6];
  const int*   ip    = (const int*)d_in[7];

  float* ws = (float*)d_ws;
  float*  wsc       = ws;                          // 16 floats (+flags)
  float*  sc        = ws + 16;                     // 32768
  float*  xq        = sc + TF;                     // 32768
  float*  pq        = xq + TF;                     // 32768
  double* osum_part = (double*)(pq + TF);          // 32 doubles (8B-aligned)
  double* pscore    = osum_part + 32;              // 2*2048 doubles
  int*    cidx      = (int*)(pscore + 2 * NS);     // 2048 ints
  float*  cw        = (float*)(cidx + NS);         // 2048 floats
  float*  partial   = cw + NS;                     // 16*32768 floats

  hipLaunchKernelGGL(k1a_sched,  dim3(1),        dim3(256), 0, stream,
                     ip, (const unsigned int*)mask, wsc);
  hipLaunchKernelGGL(k1b_tables, dim3(32),       dim3(256), 0, stream,
                     Xbar, obs, mask, timep, dega, degb, wsc, sc, xq, pq, osum_part);
  hipLaunchKernelGGL(k2_scores,  dim3(NS/4, 2),  dim3(256), 0, stream,
                     eps, sc, xq, pq, pscore);
  hipLaunchKernelGGL(k3_softmax, dim3(1),        dim3(256), 0, stream,
                     pscore, osum_part, wsc, cidx, cw);
  hipLaunchKernelGGL(k4_weighted,dim3(32, 16),   dim3(256), 0, stream,
                     eps, xq, cidx, cw, wsc, Xbar, partial);
  hipLaunchKernelGGL(k5_final,   dim3(32),       dim3(256), 0, stream,
                     partial, Xbar, obs, mask, wsc, (float*)d_out);
}

// Round 5
// 75.096 us; speedup vs baseline: 1.6700x; 1.0546x over previous
//
#include <hip/hip_runtime.h>

typedef __attribute__((ext_vector_type(4))) int   i32x4;
typedef __attribute__((ext_vector_type(4))) float f32x4;

#define TF    32768   // T*F
#define TF4   8192    // TF/4
#define NS    2048    // N samples
#define WCUT  1e-9f   // weight cutoff: skipped mass <= 2048*1e-9 ~ 2e-6

// mask accessor: isI32 ? int32[] : byte-bool[]
__device__ __forceinline__ i32x4 mload4(const void* mask, int isI32, int idx4) {
  if (isI32) return ((const i32x4*)mask)[idx4];
  unsigned int w = ((const unsigned int*)mask)[idx4];
  i32x4 r;
  r[0] = (int)(w & 0xFFu);
  r[1] = (int)((w >> 8) & 0xFFu);
  r[2] = (int)((w >> 16) & 0xFFu);
  r[3] = (int)((w >> 24) & 0xFFu);
  return r;
}

__device__ __forceinline__ double ac_fn(int t) {
  const double s = 0.008;
  double c = cos(((double)t / 1000.0 + s) / (1.0 + s) * 1.5707963267948966);
  return c * c;
}
__device__ __forceinline__ double alpha_fn(int t) {
  double beta = 1.0 - ac_fn(t + 1) / ac_fn(t);
  beta = beta < 0.0 ? 0.0 : (beta > 0.999 ? 0.999 : beta);
  return 1.0 - beta;
}

// ---------- K1a: mask-dtype probe + schedule scalars (1 block) ----------
__launch_bounds__(256)
__global__ void k1a_sched(const int* __restrict__ ip,
                          const unsigned int* __restrict__ maskw,
                          float* __restrict__ wsc) {
  const int tid = threadIdx.x;
  __shared__ int badsh;
  if (tid == 0) badsh = 0;
  __syncthreads();
  int bad = 0;
  for (int k = tid; k < TF4; k += 256)
    if (maskw[k] > 1u) bad = 1;          // int32 0/1 mask never triggers
  if (bad) atomicOr(&badsh, 1);

  const int i = ip[0];
  __shared__ double prod[256];
  double p = 1.0;
  for (int t = tid; t < i; t += 256) p *= alpha_fn(t);
  prod[tid] = p;
  __syncthreads();
  for (int s = 128; s > 0; s >>= 1) {
    if (tid < s) prod[tid] *= prod[tid + s];
    __syncthreads();
  }
  if (tid == 0) {
    double acp_im1 = prod[0];
    double ai = alpha_fn(i);
    double acp_i = acp_im1 * ai;
    wsc[0] = (float)sqrt(1.0 - acp_i);  // sigma_i
    wsc[1] = (float)acp_i;              // abar_i
    wsc[2] = (float)ai;                 // alpha_i
    wsc[3] = (float)acp_im1;            // abar_{i-1}
    ((int*)wsc)[8] = badsh ? 0 : 1;     // 1 = mask stored as int32
  }
}

// ---------- K1b: fused per-position streams + observed-const (grid 32) ----------
__launch_bounds__(256)
__global__ void k1b_tables(const float* __restrict__ xbar,
                           const float* __restrict__ obs,
                           const void* __restrict__ mask,
                           const float* __restrict__ timep,
                           const float* __restrict__ dega,
                           const float* __restrict__ degb,
                           const float* __restrict__ wsc,
                           float* __restrict__ sc, float* __restrict__ xq,
                           float* __restrict__ pq, double* __restrict__ osum_part) {
  const int tid = threadIdx.x;
  const int pos4 = blockIdx.x * 256 + tid;   // 0..8191
  const float sig = wsc[0];
  const int isI32 = ((const int*)wsc)[8];

  const int t  = pos4 >> 4;
  const int f0 = (pos4 << 2) & 63;
  const float tv = timep[t];
  f32x4 da = *(const f32x4*)(dega + f0);
  f32x4 db = *(const f32x4*)(degb + f0);
  f32x4 x  = ((const f32x4*)xbar)[pos4];
  f32x4 o  = ((const f32x4*)obs)[pos4];
  i32x4 m  = mload4(mask, isI32, pos4);

  f32x4 scv, xqv, pqv;
  float od2 = 0.f;
  #pragma unroll
  for (int c = 0; c < 4; ++c) {
    const float pr = fmaf(db[c], tv, da[c]);
    const bool mm = m[c] != 0;
    scv[c] = mm ? 0.f : sig;
    xqv[c] = mm ? 0.f : x[c];
    pqv[c] = mm ? 0.f : pr;
    float d = o[c] - pr;
    od2 += mm ? d * d : 0.f;
  }
  ((f32x4*)sc)[pos4] = scv;
  ((f32x4*)xq)[pos4] = xqv;
  ((f32x4*)pq)[pos4] = pqv;

  __shared__ double red[256];
  red[tid] = (double)od2;
  __syncthreads();
  for (int s = 128; s > 0; s >>= 1) {
    if (tid < s) red[tid] += red[tid + s];
    __syncthreads();
  }
  if (tid == 0) osum_part[blockIdx.x] = red[0];
}

// ---------- K2: per-sample score partials (4 samples x 4 k-quarters) ----------
// grid (512, 4): 2048 blocks = 8 blocks/CU; 2 positions per iter (8 eps loads
// in flight per wave-iter) for latency hiding.
__launch_bounds__(256)
__global__ void k2_scores(const float* __restrict__ eps,
                          const float* __restrict__ sc,
                          const float* __restrict__ xq,
                          const float* __restrict__ pq,
                          double* __restrict__ pscore) {
  const int tid = threadIdx.x;
  const int n0 = blockIdx.x * 4;
  const int kq = blockIdx.y;
  const int kbeg = kq * (TF4 / 4);           // 2048 positions per quarter
  const f32x4* e4 = (const f32x4*)eps;
  const f32x4* sc4 = (const f32x4*)sc;
  const f32x4* xq4 = (const f32x4*)xq;
  const f32x4* pq4 = (const f32x4*)pq;

  double acc[4] = {0.0, 0.0, 0.0, 0.0};
  #pragma unroll 2
  for (int k = kbeg + tid; k < kbeg + TF4 / 4; k += 512) {
    const int k1 = k + 256;
    f32x4 sv0 = sc4[k],  xv0 = xq4[k],  pv0 = pq4[k];
    f32x4 sv1 = sc4[k1], xv1 = xq4[k1], pv1 = pq4[k1];
    #pragma unroll
    for (int r = 0; r < 4; ++r) {
      const size_t row = (size_t)(n0 + r) * TF4;
      f32x4 e0 = e4[row + k];
      f32x4 e1 = e4[row + k1];
      float s = 0.f;
      #pragma unroll
      for (int c = 0; c < 4; ++c) {
        float v = fmaf(e0[c], sv0[c], xv0[c]);
        v = fminf(fmaxf(v, -1.f), 1.f);
        float d = v - pv0[c];
        s = fmaf(d, d, s);
      }
      #pragma unroll
      for (int c = 0; c < 4; ++c) {
        float v = fmaf(e1[c], sv1[c], xv1[c]);
        v = fminf(fmaxf(v, -1.f), 1.f);
        float d = v - pv1[c];
        s = fmaf(d, d, s);
      }
      acc[r] += (double)s;
    }
  }
  __shared__ double red[4 * 256];
  #pragma unroll
  for (int r = 0; r < 4; ++r) red[r * 256 + tid] = acc[r];
  __syncthreads();
  for (int s = 128; s > 0; s >>= 1) {
    if (tid < s) {
      #pragma unroll
      for (int r = 0; r < 4; ++r) red[r * 256 + tid] += red[r * 256 + tid + s];
    }
    __syncthreads();
  }
  if (tid < 4) pscore[kq * NS + n0 + tid] = red[tid * 256];
}

// ---------- K3: softmax + deterministic compaction ----------
__launch_bounds__(256)
__global__ void k3_softmax(const double* __restrict__ pscore,
                           const double* __restrict__ osum_part,
                           float* __restrict__ wsc,
                           int* __restrict__ cidx, float* __restrict__ cw) {
  const int tid = threadIdx.x;
  __shared__ double red[256];

  // observed-constant
  double osum = 0.0;
  if (tid < 32) osum = osum_part[tid];
  red[tid] = osum; __syncthreads();
  for (int st = 128; st > 0; st >>= 1) { if (tid < st) red[tid] += red[tid + st]; __syncthreads(); }
  osum = red[0];
  __syncthreads();

  float s[8];
  #pragma unroll
  for (int j = 0; j < 8; ++j) {
    int n = tid + 256 * j;
    double t = pscore[n] + pscore[NS + n] + pscore[2 * NS + n] + pscore[3 * NS + n];
    s[j] = -(float)((t + osum) * (1.0 / 32768.0));
  }
  double t = 0.0;
  #pragma unroll
  for (int j = 0; j < 8; ++j) t += (double)s[j];
  red[tid] = t; __syncthreads();
  for (int st = 128; st > 0; st >>= 1) { if (tid < st) red[tid] += red[tid + st]; __syncthreads(); }
  const float mean = (float)(red[0] * (1.0 / 2048.0));
  __syncthreads();
  double v = 0.0;
  #pragma unroll
  for (int j = 0; j < 8; ++j) { float d = s[j] - mean; v += (double)d * (double)d; }
  red[tid] = v; __syncthreads();
  for (int st = 128; st > 0; st >>= 1) { if (tid < st) red[tid] += red[tid + st]; __syncthreads(); }
  float stdv = (float)sqrt(red[0] / 2047.0);   // ddof=1
  stdv = fmaxf(stdv, 1e-4f);
  const float inv = 10.0f / stdv;              // /std /0.1
  float lp[8];
  double mx = -1e300;
  #pragma unroll
  for (int j = 0; j < 8; ++j) { lp[j] = (s[j] - mean) * inv; mx = fmax(mx, (double)lp[j]); }
  __syncthreads();
  red[tid] = mx; __syncthreads();
  for (int st = 128; st > 0; st >>= 1) { if (tid < st) red[tid] = fmax(red[tid], red[tid + st]); __syncthreads(); }
  const float M = (float)red[0];
  __syncthreads();
  float ev[8]; double es = 0.0;
  #pragma unroll
  for (int j = 0; j < 8; ++j) { ev[j] = expf(lp[j] - M); es += (double)ev[j]; }
  red[tid] = es; __syncthreads();
  for (int st = 128; st > 0; st >>= 1) { if (tid < st) red[tid] += red[tid + st]; __syncthreads(); }
  const float invS = (float)(1.0 / red[0]);

  // weights + deterministic compaction (prefix scan over per-thread counts)
  float w[8]; int keep[8]; int c = 0;
  #pragma unroll
  for (int j = 0; j < 8; ++j) {
    w[j] = ev[j] * invS;
    keep[j] = w[j] > WCUT;
    c += keep[j];
  }
  __shared__ int cnt[256];
  cnt[tid] = c; __syncthreads();
  for (int off = 1; off < 256; off <<= 1) {
    int vv = (tid >= off) ? cnt[tid - off] : 0;
    __syncthreads();
    cnt[tid] += vv;
    __syncthreads();
  }
  int base = cnt[tid] - c;              // exclusive prefix
  #pragma unroll
  for (int j = 0; j < 8; ++j) {
    if (keep[j]) {
      cidx[base] = tid + 256 * j;
      cw[base] = w[j];
      ++base;
    }
  }
  if (tid == 255) ((int*)wsc)[9] = cnt[255];   // Nk
}

// ---------- K4: weighted sum over kept samples only (unroll 2) ----------
__launch_bounds__(256)
__global__ void k4_weighted(const float* __restrict__ eps,
                            const int* __restrict__ cidx,
                            const float* __restrict__ cw,
                            const float* __restrict__ wsc,
                            const float* __restrict__ xbar,
                            float* __restrict__ partial) {
  const int tid = threadIdx.x;
  const int pos4 = blockIdx.x * 256 + tid;   // 0..8191
  const int g = blockIdx.y;                  // 0..15
  const int Nk = ((const int*)wsc)[9];
  const float sig = wsc[0];
  const f32x4* e4 = (const f32x4*)eps;
  f32x4 xf = ((const f32x4*)xbar)[pos4];
  f32x4 acc = {0.f, 0.f, 0.f, 0.f};
  int j = g;
  for (; j + 16 < Nk; j += 32) {
    const float w0 = cw[j];
    const int   n0 = cidx[j];
    const float w1 = cw[j + 16];
    const int   n1 = cidx[j + 16];
    f32x4 e0 = e4[(size_t)n0 * TF4 + pos4];
    f32x4 e1 = e4[(size_t)n1 * TF4 + pos4];
    #pragma unroll
    for (int c = 0; c < 4; ++c) {
      float v = fmaf(e0[c], sig, xf[c]);
      v = fminf(fmaxf(v, -1.f), 1.f);
      acc[c] = fmaf(w0, v, acc[c]);
    }
    #pragma unroll
    for (int c = 0; c < 4; ++c) {
      float v = fmaf(e1[c], sig, xf[c]);
      v = fminf(fmaxf(v, -1.f), 1.f);
      acc[c] = fmaf(w1, v, acc[c]);
    }
  }
  for (; j < Nk; j += 16) {
    const float w = cw[j];
    const int n = cidx[j];
    f32x4 e = e4[(size_t)n * TF4 + pos4];
    #pragma unroll
    for (int c = 0; c < 4; ++c) {
      float v = fmaf(e[c], sig, xf[c]);
      v = fminf(fmaxf(v, -1.f), 1.f);
      acc[c] = fmaf(w, v, acc[c]);
    }
  }
  ((f32x4*)partial)[(size_t)g * TF4 + pos4] = acc;
}

// ---------- K5: reduce partials + final combine -> f32 out ----------
__launch_bounds__(256)
__global__ void k5_final(const float* __restrict__ partial,
                         const float* __restrict__ xbar,
                         const float* __restrict__ obs,
                         const void* __restrict__ mask,
                         const float* __restrict__ wsc,
                         float* __restrict__ out) {
  const int pos4 = blockIdx.x * 256 + threadIdx.x;  // grid 32
  const f32x4* p4 = (const f32x4*)partial;
  f32x4 w = {0.f, 0.f, 0.f, 0.f};
  #pragma unroll
  for (int g = 0; g < 16; ++g) {
    f32x4 a = p4[(size_t)g * TF4 + pos4];
    #pragma unroll
    for (int c = 0; c < 4; ++c) w[c] += a[c];
  }
  const float abar = wsc[1];
  const float sa = sqrtf(abar);
  const float ra = 1.f / sqrtf(wsc[2]);
  const float rb = 1.f / sqrtf(wsc[3]);
  const int isI32 = ((const int*)wsc)[8];
  f32x4 xf = ((const f32x4*)xbar)[pos4];
  f32x4 ov = ((const f32x4*)obs)[pos4];
  i32x4 m = mload4(mask, isI32, pos4);
  f32x4 res;
  #pragma unroll
  for (int c = 0; c < 4; ++c) {
    const float Yi = sa * xf[c];
    const float scv = (-Yi + sa * w[c]) / (1.f - abar);
    const float xim1 = (Yi + (1.f - abar) * scv) * ra;
    res[c] = m[c] ? ov[c] : (xim1 * rb);
  }
  ((f32x4*)out)[pos4] = res;
}

extern "C" void kernel_launch(void* const* d_in, const int* in_sizes, int n_in,
                              void* d_out, int out_size, void* d_ws, size_t ws_size,
                              hipStream_t stream) {
  const float* Xbar  = (const float*)d_in[0];
  const float* obs   = (const float*)d_in[1];
  const float* timep = (const float*)d_in[2];
  const void*  mask  = d_in[3];
  const float* eps   = (const float*)d_in[4];
  const float* dega  = (const float*)d_in[5];
  const float* degb  = (const float*)d_in[6];
  const int*   ip    = (const int*)d_in[7];

  float* ws = (float*)d_ws;
  float*  wsc       = ws;                          // 16 floats (+flags)
  float*  sc        = ws + 16;                     // 32768
  float*  xq        = sc + TF;                     // 32768
  float*  pq        = xq + TF;                     // 32768
  double* osum_part = (double*)(pq + TF);          // 32 doubles (8B-aligned)
  double* pscore    = osum_part + 32;              // 4*2048 doubles
  int*    cidx      = (int*)(pscore + 4 * NS);     // 2048 ints
  float*  cw        = (float*)(cidx + NS);         // 2048 floats
  float*  partial   = cw + NS;                     // 16*32768 floats

  hipLaunchKernelGGL(k1a_sched,  dim3(1),        dim3(256), 0, stream,
                     ip, (const unsigned int*)mask, wsc);
  hipLaunchKernelGGL(k1b_tables, dim3(32),       dim3(256), 0, stream,
                     Xbar, obs, mask, timep, dega, degb, wsc, sc, xq, pq, osum_part);
  hipLaunchKernelGGL(k2_scores,  dim3(NS/4, 4),  dim3(256), 0, stream,
                     eps, sc, xq, pq, pscore);
  hipLaunchKernelGGL(k3_softmax, dim3(1),        dim3(256), 0, stream,
                     pscore, osum_part, wsc, cidx, cw);
  hipLaunchKernelGGL(k4_weighted,dim3(32, 16),   dim3(256), 0, stream,
                     eps, cidx, cw, wsc, Xbar, partial);
  hipLaunchKernelGGL(k5_final,   dim3(32),       dim3(256), 0, stream,
                     partial, Xbar, obs, mask, wsc, (float*)d_out);
}

// Round 6
// 71.382 us; speedup vs baseline: 1.7569x; 1.0520x over previous
//
#include <hip/hip_runtime.h>

typedef __attribute__((ext_vector_type(4))) int   i32x4;
typedef __attribute__((ext_vector_type(4))) float f32x4;

#define TF    32768   // T*F
#define TF4   8192    // TF/4
#define NS    2048    // N samples
#define NG    32      // K4 sample-groups
#define WCUT  1e-9f   // weight cutoff: skipped mass <= 2048*1e-9 ~ 2e-6

// mask accessor: isI32 ? int32[] : byte-bool[]
__device__ __forceinline__ i32x4 mload4(const void* mask, int isI32, int idx4) {
  if (isI32) return ((const i32x4*)mask)[idx4];
  unsigned int w = ((const unsigned int*)mask)[idx4];
  i32x4 r;
  r[0] = (int)(w & 0xFFu);
  r[1] = (int)((w >> 8) & 0xFFu);
  r[2] = (int)((w >> 16) & 0xFFu);
  r[3] = (int)((w >> 24) & 0xFFu);
  return r;
}

__device__ __forceinline__ double ac_fn(int t) {
  const double s = 0.008;
  double c = cos(((double)t / 1000.0 + s) / (1.0 + s) * 1.5707963267948966);
  return c * c;
}
__device__ __forceinline__ double alpha_fn(int t) {
  double beta = 1.0 - ac_fn(t + 1) / ac_fn(t);
  beta = beta < 0.0 ? 0.0 : (beta > 0.999 ? 0.999 : beta);
  return 1.0 - beta;
}

// ---------- K1: fused probe + schedule + tables (grid 32) ----------
// Every block redundantly probes mask dtype and computes the schedule
// (cheap: ~2 f64 cos per thread); block 0 publishes wsc for K4/K5.
// Tables fold the observed-position constant into pq:
//   missing:  sc=sig, xq=x, pq=pred          -> d = clip(e*sig+x) - pred
//   observed: sc=0,   xq=0, pq=(obs-pred)    -> v=0, d^2 = (obs-pred)^2
__launch_bounds__(256)
__global__ void k1_fused(const int* __restrict__ ip,
                         const unsigned int* __restrict__ maskw,
                         const float* __restrict__ timep,
                         const float* __restrict__ dega,
                         const float* __restrict__ degb,
                         const float* __restrict__ xbar,
                         const float* __restrict__ obs,
                         const void* __restrict__ mask,
                         float* __restrict__ wsc,
                         float* __restrict__ sc, float* __restrict__ xq,
                         float* __restrict__ pq) {
  const int tid = threadIdx.x;
  __shared__ int badsh;
  __shared__ double prod[256];
  __shared__ float ssig;
  __shared__ int sIsI32;
  if (tid == 0) badsh = 0;
  __syncthreads();
  int bad = 0;
  for (int k = tid; k < TF4; k += 256)
    if (maskw[k] > 1u) bad = 1;           // int32 0/1 mask never triggers
  if (bad) atomicOr(&badsh, 1);

  const int i = ip[0];
  double p = 1.0;
  for (int t = tid; t < i; t += 256) p *= alpha_fn(t);
  prod[tid] = p;
  __syncthreads();
  for (int s = 128; s > 0; s >>= 1) {
    if (tid < s) prod[tid] *= prod[tid + s];
    __syncthreads();
  }
  if (tid == 0) {
    double acp_im1 = prod[0];
    double ai = alpha_fn(i);
    double acp_i = acp_im1 * ai;
    float sig = (float)sqrt(1.0 - acp_i);
    ssig = sig;
    sIsI32 = badsh ? 0 : 1;
    if (blockIdx.x == 0) {
      wsc[0] = sig;                 // sigma_i
      wsc[1] = (float)acp_i;        // abar_i
      wsc[2] = (float)ai;           // alpha_i
      wsc[3] = (float)acp_im1;      // abar_{i-1}
      ((int*)wsc)[8] = badsh ? 0 : 1;
    }
  }
  __syncthreads();
  const float sig = ssig;
  const int isI32 = sIsI32;

  const int pos4 = blockIdx.x * 256 + tid;   // 0..8191
  const int t  = pos4 >> 4;
  const int f0 = (pos4 << 2) & 63;
  const float tv = timep[t];
  f32x4 da = *(const f32x4*)(dega + f0);
  f32x4 db = *(const f32x4*)(degb + f0);
  f32x4 x  = ((const f32x4*)xbar)[pos4];
  f32x4 o  = ((const f32x4*)obs)[pos4];
  i32x4 m  = mload4(mask, isI32, pos4);

  f32x4 scv, xqv, pqv;
  #pragma unroll
  for (int c = 0; c < 4; ++c) {
    const float pr = fmaf(db[c], tv, da[c]);
    const bool mm = m[c] != 0;
    scv[c] = mm ? 0.f : sig;
    xqv[c] = mm ? 0.f : x[c];
    pqv[c] = mm ? (o[c] - pr) : pr;
  }
  ((f32x4*)sc)[pos4] = scv;
  ((f32x4*)xq)[pos4] = xqv;
  ((f32x4*)pq)[pos4] = pqv;
}

// ---------- K2: per-sample score partials (4 samples x 4 k-quarters) ----------
__launch_bounds__(256)
__global__ void k2_scores(const float* __restrict__ eps,
                          const float* __restrict__ sc,
                          const float* __restrict__ xq,
                          const float* __restrict__ pq,
                          double* __restrict__ pscore) {
  const int tid = threadIdx.x;
  const int n0 = blockIdx.x * 4;
  const int kq = blockIdx.y;
  const int kbeg = kq * (TF4 / 4);           // 2048 positions per quarter
  const f32x4* e4 = (const f32x4*)eps;
  const f32x4* sc4 = (const f32x4*)sc;
  const f32x4* xq4 = (const f32x4*)xq;
  const f32x4* pq4 = (const f32x4*)pq;

  double acc[4] = {0.0, 0.0, 0.0, 0.0};
  #pragma unroll 2
  for (int k = kbeg + tid; k < kbeg + TF4 / 4; k += 512) {
    const int k1 = k + 256;
    f32x4 sv0 = sc4[k],  xv0 = xq4[k],  pv0 = pq4[k];
    f32x4 sv1 = sc4[k1], xv1 = xq4[k1], pv1 = pq4[k1];
    #pragma unroll
    for (int r = 0; r < 4; ++r) {
      const size_t row = (size_t)(n0 + r) * TF4;
      f32x4 e0 = e4[row + k];
      f32x4 e1 = e4[row + k1];
      float s = 0.f;
      #pragma unroll
      for (int c = 0; c < 4; ++c) {
        float v = fmaf(e0[c], sv0[c], xv0[c]);
        v = fminf(fmaxf(v, -1.f), 1.f);
        float d = v - pv0[c];
        s = fmaf(d, d, s);
      }
      #pragma unroll
      for (int c = 0; c < 4; ++c) {
        float v = fmaf(e1[c], sv1[c], xv1[c]);
        v = fminf(fmaxf(v, -1.f), 1.f);
        float d = v - pv1[c];
        s = fmaf(d, d, s);
      }
      acc[r] += (double)s;
    }
  }
  __shared__ double red[4 * 256];
  #pragma unroll
  for (int r = 0; r < 4; ++r) red[r * 256 + tid] = acc[r];
  __syncthreads();
  for (int s = 128; s > 0; s >>= 1) {
    if (tid < s) {
      #pragma unroll
      for (int r = 0; r < 4; ++r) red[r * 256 + tid] += red[r * 256 + tid + s];
    }
    __syncthreads();
  }
  if (tid < 4) pscore[kq * NS + n0 + tid] = red[tid * 256];
}

// ---------- K3: softmax + deterministic compaction ----------
__launch_bounds__(256)
__global__ void k3_softmax(const double* __restrict__ pscore,
                           float* __restrict__ wsc,
                           int* __restrict__ cidx, float* __restrict__ cw) {
  const int tid = threadIdx.x;
  __shared__ double red[256];

  float s[8];
  #pragma unroll
  for (int j = 0; j < 8; ++j) {
    int n = tid + 256 * j;
    double t = pscore[n] + pscore[NS + n] + pscore[2 * NS + n] + pscore[3 * NS + n];
    s[j] = -(float)(t * (1.0 / 32768.0));
  }
  double t = 0.0;
  #pragma unroll
  for (int j = 0; j < 8; ++j) t += (double)s[j];
  red[tid] = t; __syncthreads();
  for (int st = 128; st > 0; st >>= 1) { if (tid < st) red[tid] += red[tid + st]; __syncthreads(); }
  const float mean = (float)(red[0] * (1.0 / 2048.0));
  __syncthreads();
  double v = 0.0;
  #pragma unroll
  for (int j = 0; j < 8; ++j) { float d = s[j] - mean; v += (double)d * (double)d; }
  red[tid] = v; __syncthreads();
  for (int st = 128; st > 0; st >>= 1) { if (tid < st) red[tid] += red[tid + st]; __syncthreads(); }
  float stdv = (float)sqrt(red[0] / 2047.0);   // ddof=1
  stdv = fmaxf(stdv, 1e-4f);
  const float inv = 10.0f / stdv;              // /std /0.1
  float lp[8];
  double mx = -1e300;
  #pragma unroll
  for (int j = 0; j < 8; ++j) { lp[j] = (s[j] - mean) * inv; mx = fmax(mx, (double)lp[j]); }
  __syncthreads();
  red[tid] = mx; __syncthreads();
  for (int st = 128; st > 0; st >>= 1) { if (tid < st) red[tid] = fmax(red[tid], red[tid + st]); __syncthreads(); }
  const float M = (float)red[0];
  __syncthreads();
  float ev[8]; double es = 0.0;
  #pragma unroll
  for (int j = 0; j < 8; ++j) { ev[j] = expf(lp[j] - M); es += (double)ev[j]; }
  red[tid] = es; __syncthreads();
  for (int st = 128; st > 0; st >>= 1) { if (tid < st) red[tid] += red[tid + st]; __syncthreads(); }
  const float invS = (float)(1.0 / red[0]);

  // weights + deterministic compaction (prefix scan over per-thread counts)
  float w[8]; int keep[8]; int c = 0;
  #pragma unroll
  for (int j = 0; j < 8; ++j) {
    w[j] = ev[j] * invS;
    keep[j] = w[j] > WCUT;
    c += keep[j];
  }
  __shared__ int cnt[256];
  cnt[tid] = c; __syncthreads();
  for (int off = 1; off < 256; off <<= 1) {
    int vv = (tid >= off) ? cnt[tid - off] : 0;
    __syncthreads();
    cnt[tid] += vv;
    __syncthreads();
  }
  int base = cnt[tid] - c;              // exclusive prefix
  #pragma unroll
  for (int j = 0; j < 8; ++j) {
    if (keep[j]) {
      cidx[base] = tid + 256 * j;
      cw[base] = w[j];
      ++base;
    }
  }
  if (tid == 255) ((int*)wsc)[9] = cnt[255];   // Nk
}

// ---------- K4: weighted sum over kept samples (32 groups, unroll 2) ----------
__launch_bounds__(256)
__global__ void k4_weighted(const float* __restrict__ eps,
                            const int* __restrict__ cidx,
                            const float* __restrict__ cw,
                            const float* __restrict__ wsc,
                            const float* __restrict__ xbar,
                            float* __restrict__ partial) {
  const int tid = threadIdx.x;
  const int pos4 = blockIdx.x * 256 + tid;   // 0..8191
  const int g = blockIdx.y;                  // 0..NG-1
  const int Nk = ((const int*)wsc)[9];
  const float sig = wsc[0];
  const f32x4* e4 = (const f32x4*)eps;
  f32x4 xf = ((const f32x4*)xbar)[pos4];
  f32x4 acc = {0.f, 0.f, 0.f, 0.f};
  int j = g;
  for (; j + NG < Nk; j += 2 * NG) {
    const float w0 = cw[j];
    const int   n0 = cidx[j];
    const float w1 = cw[j + NG];
    const int   n1 = cidx[j + NG];
    f32x4 e0 = e4[(size_t)n0 * TF4 + pos4];
    f32x4 e1 = e4[(size_t)n1 * TF4 + pos4];
    #pragma unroll
    for (int c = 0; c < 4; ++c) {
      float v = fmaf(e0[c], sig, xf[c]);
      v = fminf(fmaxf(v, -1.f), 1.f);
      acc[c] = fmaf(w0, v, acc[c]);
    }
    #pragma unroll
    for (int c = 0; c < 4; ++c) {
      float v = fmaf(e1[c], sig, xf[c]);
      v = fminf(fmaxf(v, -1.f), 1.f);
      acc[c] = fmaf(w1, v, acc[c]);
    }
  }
  for (; j < Nk; j += NG) {
    const float w = cw[j];
    const int n = cidx[j];
    f32x4 e = e4[(size_t)n * TF4 + pos4];
    #pragma unroll
    for (int c = 0; c < 4; ++c) {
      float v = fmaf(e[c], sig, xf[c]);
      v = fminf(fmaxf(v, -1.f), 1.f);
      acc[c] = fmaf(w, v, acc[c]);
    }
  }
  ((f32x4*)partial)[(size_t)g * TF4 + pos4] = acc;
}

// ---------- K5: reduce partials + final combine -> f32 out ----------
__launch_bounds__(256)
__global__ void k5_final(const float* __restrict__ partial,
                         const float* __restrict__ xbar,
                         const float* __restrict__ obs,
                         const void* __restrict__ mask,
                         const float* __restrict__ wsc,
                         float* __restrict__ out) {
  const int pos4 = blockIdx.x * 256 + threadIdx.x;  // grid 32
  const f32x4* p4 = (const f32x4*)partial;
  f32x4 w = {0.f, 0.f, 0.f, 0.f};
  #pragma unroll
  for (int g = 0; g < NG; ++g) {
    f32x4 a = p4[(size_t)g * TF4 + pos4];
    #pragma unroll
    for (int c = 0; c < 4; ++c) w[c] += a[c];
  }
  const float abar = wsc[1];
  const float sa = sqrtf(abar);
  const float ra = 1.f / sqrtf(wsc[2]);
  const float rb = 1.f / sqrtf(wsc[3]);
  const int isI32 = ((const int*)wsc)[8];
  f32x4 xf = ((const f32x4*)xbar)[pos4];
  f32x4 ov = ((const f32x4*)obs)[pos4];
  i32x4 m = mload4(mask, isI32, pos4);
  f32x4 res;
  #pragma unroll
  for (int c = 0; c < 4; ++c) {
    const float Yi = sa * xf[c];
    const float scv = (-Yi + sa * w[c]) / (1.f - abar);
    const float xim1 = (Yi + (1.f - abar) * scv) * ra;
    res[c] = m[c] ? ov[c] : (xim1 * rb);
  }
  ((f32x4*)out)[pos4] = res;
}

extern "C" void kernel_launch(void* const* d_in, const int* in_sizes, int n_in,
                              void* d_out, int out_size, void* d_ws, size_t ws_size,
                              hipStream_t stream) {
  const float* Xbar  = (const float*)d_in[0];
  const float* obs   = (const float*)d_in[1];
  const float* timep = (const float*)d_in[2];
  const void*  mask  = d_in[3];
  const float* eps   = (const float*)d_in[4];
  const float* dega  = (const float*)d_in[5];
  const float* degb  = (const float*)d_in[6];
  const int*   ip    = (const int*)d_in[7];

  float* ws = (float*)d_ws;
  float*  wsc       = ws;                          // 16 floats (+flags)
  float*  sc        = ws + 16;                     // 32768
  float*  xq        = sc + TF;                     // 32768
  float*  pq        = xq + TF;                     // 32768
  double* pscore    = (double*)(pq + TF);          // 4*2048 doubles (8B-aligned)
  int*    cidx      = (int*)(pscore + 4 * NS);     // 2048 ints
  float*  cw        = (float*)(cidx + NS);         // 2048 floats
  float*  partial   = cw + NS;                     // NG*32768 floats (4 MiB)

  hipLaunchKernelGGL(k1_fused,   dim3(32),       dim3(256), 0, stream,
                     ip, (const unsigned int*)mask, timep, dega, degb,
                     Xbar, obs, mask, wsc, sc, xq, pq);
  hipLaunchKernelGGL(k2_scores,  dim3(NS/4, 4),  dim3(256), 0, stream,
                     eps, sc, xq, pq, pscore);
  hipLaunchKernelGGL(k3_softmax, dim3(1),        dim3(256), 0, stream,
                     pscore, wsc, cidx, cw);
  hipLaunchKernelGGL(k4_weighted,dim3(32, NG),   dim3(256), 0, stream,
                     eps, cidx, cw, wsc, Xbar, partial);
  hipLaunchKernelGGL(k5_final,   dim3(32),       dim3(256), 0, stream,
                     partial, Xbar, obs, mask, wsc, (float*)d_out);
}